// Round 5
// baseline (1528.327 us; speedup 1.0000x reference)
//
#include <hip/hip_runtime.h>
#include <cstdint>
#include <cstddef>
#include <cmath>

typedef unsigned short u16;
typedef short v8s __attribute__((ext_vector_type(8)));
typedef float v4f __attribute__((ext_vector_type(4)));

constexpr int SEQ = 4096;
constexpr int FEAT = 2048;
constexpr int F3 = 6144;

// ---------- helpers ----------

__device__ __forceinline__ u16 f2bf(float f) {
  union { float f; uint32_t u; } v; v.f = f;
  uint32_t r = v.u + 0x7FFFu + ((v.u >> 16) & 1u);  // round-to-nearest-even
  return (u16)(r >> 16);
}

__device__ __forceinline__ float bf2f(u16 s) {
  union { uint32_t u; float f; } v; v.u = ((uint32_t)s) << 16;
  return v.f;
}

// async global->LDS, 16B per lane; lds dest is wave-uniform base (HW: base+lane*16)
__device__ __forceinline__ void gld_lds16(const u16* g, u16* l) {
  __builtin_amdgcn_global_load_lds(
      (const __attribute__((address_space(1))) void*)g,
      (__attribute__((address_space(3))) void*)l, 16, 0, 0);
}

// ---------- conversion / transpose ----------

__global__ void cvt_f32_bf16(const float* __restrict__ in, u16* __restrict__ out, int n8) {
  int i = blockIdx.x * 256 + threadIdx.x;
  if (i >= n8) return;
  const float4* p = (const float4*)in + (size_t)i * 2;
  float4 a = p[0], b = p[1];
  union { u16 s[8]; uint4 v; } u;
  u.s[0] = f2bf(a.x); u.s[1] = f2bf(a.y); u.s[2] = f2bf(a.z); u.s[3] = f2bf(a.w);
  u.s[4] = f2bf(b.x); u.s[5] = f2bf(b.y); u.s[6] = f2bf(b.z); u.s[7] = f2bf(b.w);
  *(uint4*)(out + (size_t)i * 8) = u.v;
}

__global__ void transp_f2b(const float* __restrict__ in, int ldin,
                           u16* __restrict__ out, int ldout) {
  __shared__ float tile[32][33];
  int c0 = blockIdx.x * 32, r0 = blockIdx.y * 32;
  int tx = threadIdx.x, ty = threadIdx.y;
#pragma unroll
  for (int p = 0; p < 4; ++p)
    tile[ty + 8 * p][tx] = in[(size_t)(r0 + ty + 8 * p) * ldin + c0 + tx];
  __syncthreads();
#pragma unroll
  for (int p = 0; p < 4; ++p)
    out[(size_t)(c0 + ty + 8 * p) * ldout + r0 + tx] = f2bf(tile[tx][ty + 8 * p]);
}

__global__ void transp_b2b(const u16* __restrict__ in, int ldin,
                           u16* __restrict__ out, int ldout) {
  __shared__ u16 tile[32][33];
  int c0 = blockIdx.x * 32, r0 = blockIdx.y * 32;
  int tx = threadIdx.x, ty = threadIdx.y;
#pragma unroll
  for (int p = 0; p < 4; ++p)
    tile[ty + 8 * p][tx] = in[(size_t)(r0 + ty + 8 * p) * ldin + c0 + tx];
  __syncthreads();
#pragma unroll
  for (int p = 0; p < 4; ++p)
    out[(size_t)(c0 + ty + 8 * p) * ldout + r0 + tx] = tile[tx][ty + 8 * p];
}

// ---------- gemmw: C[M,N] = A[M,K] * B[N,K]^T  (bf16 in, k contiguous) ----------
// Tile 128(M)x256(N), BK=32, 256 thr = 4 waves; each wave owns 128x64.
// KEY (r5): B is PRIVATE per wave (disjoint 64-col slices) -> B never goes
// through LDS. A (shared 4-way) stays in LDS (3-buf rotation, 8KB/buf = 24KB
// -> 3 blocks/CU, __launch_bounds__(256,3)). B loads global->reg in the MFMA
// fragment layout (16B/lane, k-contiguous), double-buffered in registers via
// 2x-unrolled loop (nt always even). LDS traffic per block-phase drops
// 72KB -> 40KB: MFMA pipe (620cyc) now exceeds LDS pipe (~440cyc).
// Phase p (one 32-K tile): STAGE_A(p+2) [2 gld_lds16] | LOADB_G(p+1) [4
//   global dwordx4 -> regs] | LOADA(p) [8 ds_read_b128] | 32 MFMA (B regs
//   loaded last phase) | vmcnt(6) | s_barrier.
// vmcnt-safety: exactly 6 VMEM ops per phase (barriers pin membership) =>
// vmcnt(6) pre-barrier proves A(p+1) (issued phase p-1, older) landed for
// ALL waves after the barrier. B-reg consumption is compiler-waited.
// A-overwrite safety: STAGE_A(p+2) hits the buf read at p-1; those ds_reads
// drained (lgkm before MFMA) before their wave crossed BAR(p-1).
// LDS swizzle (proven, conflicts=0): row of 32 elems = 4 chunks of 16B;
// logical chunk c at physical (c + (row>>1))&3; global source pre-rotated.
// MODE: 0 = rect grid (XCD col-major swizzle if SWZ: same-XCD share B panel);
//       1 = att@v flat LPT grid (512 blocks, longest-K first, fp32 atomicAdd);
//       2 = compact causal triangular grid (bj <= bi/2), full K.

#define BARW() asm volatile("s_barrier" ::: "memory")
#define VMC6() asm volatile("s_waitcnt vmcnt(6)" ::: "memory")

#define STAGE_A(SB, KO) do { \
  u16* Lb = &Aldss[SB][0] + w * 512; \
  gld_lds16(pA0 + (KO), Lb); \
  gld_lds16(pA0 + (size_t)64 * LDA_ + (KO), Lb + 2048); \
} while (0)

#define LOADA(BUF) do { _Pragma("unroll") \
  for (int mi = 0; mi < 8; ++mi) \
    af[mi] = *(const v8s*)(&Aldss[BUF][0] + (mi * 16 + lm) * 32 + lqs); \
} while (0)

#define LOADB_G(DST, KO) do { _Pragma("unroll") \
  for (int ni = 0; ni < 4; ++ni) \
    DST[ni] = *(const v8s*)(pBF + (size_t)(ni * 16) * LDB_ + (KO)); \
} while (0)

#define MMAW(BF) do { \
  __builtin_amdgcn_s_setprio(1); \
  _Pragma("unroll") \
  for (int mi = 0; mi < 8; ++mi) { _Pragma("unroll") \
    for (int ni = 0; ni < 4; ++ni) \
      acc[mi][ni] = __builtin_amdgcn_mfma_f32_16x16x32_bf16(af[mi], BF[ni], acc[mi][ni], 0, 0, 0); } \
  __builtin_amdgcn_s_setprio(0); \
} while (0)

__device__ __forceinline__ int tri_S(int v) {  // #blocks before row-block v
  const int u = v >> 1;
  return (v & 1) ? (u + 1) * (u + 1) : u * u + u;
}

template<int LDA_, int LDB_, int LDC_, int OUTMODE /*0=bf16 store, 1=fp32 atomicAdd*/,
         int ADDB, int MODE, int SWZ>
__global__ __launch_bounds__(256, 3) void gemmw(
    const u16* __restrict__ A, const u16* __restrict__ B,
    void* __restrict__ Cv, int K,
    const float* __restrict__ bias, float scale) {
  int bi, bj, ks, ke;
  if (MODE == 2) {
    // compact causal triangular grid: row-block bi (128 rows) needs
    // col-blocks bj <= bi/2 (256 cols). 272 blocks, XCD-chunked (272%8==0).
    const int b = blockIdx.x;
    const int cpx = (int)gridDim.x >> 3;
    const int s = (b & 7) * cpx + (b >> 3);
    bi = 2 * (int)sqrtf((float)s);
    while (tri_S(bi + 1) <= s) ++bi;
    while (tri_S(bi) > s) --bi;
    bj = s - tri_S(bi);
    ks = 0; ke = K;
  } else if (MODE == 1) {
    // flat LPT grid: 512 blocks, descending K (longest first)
    const int f = blockIdx.x;
    bi = ((int)gridDim.x >> 4) - 1 - (f >> 4);   // 31..0
    bj = (f >> 1) & 7;
    const int z = f & 1;
    const int kq = (bi + 1) * 64;
    ks = z ? kq : 0;  ke = ks + kq;              // nt = 2*(bi+1), even, >= 2
  } else {
    if (SWZ) {
      // column-major within XCD chunk: same-XCD neighbors share the B panel
      const int gx = gridDim.x, gy = gridDim.y;
      const int b = blockIdx.y * gx + blockIdx.x;
      const int cpx = (gx * gy) >> 3;            // nwg % 8 == 0
      const int s = (b & 7) * cpx + (b >> 3);
      bi = s % gy;  bj = s / gy;
    } else { bj = blockIdx.x; bi = blockIdx.y; }
    ks = 0; ke = K;
  }
  const int i0 = bi * 128, j0 = bj * 256;

  __shared__ u16 Aldss[3][4096];   // 3 bufs x (128 rows x 32 k) = 24 KiB

  const int t = threadIdx.x;
  const int w = t >> 6, l = t & 63;
  const int lm = l & 15, lq = l >> 4;
  // fragment read: physical chunk = (lq + (row>>1)) & 3; row bases are
  // multiples of 8 => (row>>1)&3 == (lm>>1)&3
  const int lqs = ((lq + (lm >> 1)) & 3) * 8;

  // A staging: wave w covers rows [w*16, w*16+16) and +64; lane l: row =
  // base + (l>>2), physical chunk l&3, logical chunk = ((l&3)-((row>>1)&3))&3.
  const int rA = w * 16 + (l >> 2);
  const int cA = ((((l & 3) - ((rA >> 1) & 3)) & 3)) * 8;
  const u16* pA0 = A + (size_t)(i0 + rA) * LDA_ + cA;
  // B direct-to-reg: lane reads 16B at (row = j0 + w*64 + ni*16 + lm, k + lq*8)
  const u16* pBF = B + (size_t)(j0 + w * 64 + lm) * LDB_ + lq * 8;

  v4f acc[8][4];
#pragma unroll
  for (int a = 0; a < 8; ++a)
#pragma unroll
    for (int b2 = 0; b2 < 4; ++b2)
      acc[a][b2] = v4f{0.f, 0.f, 0.f, 0.f};

  v8s af[8], bfU[4], bfV[4];

  // prologue: stage A tiles 0,1; load B tile 0 -> bfU.
  // vmcnt(6) leaves {A(1):2, B(0):4} in flight => A(0) landed.
  STAGE_A(0, ks); STAGE_A(1, ks + 32);
  LOADB_G(bfU, ks);
  VMC6(); BARW();

  const int nt = (ke - ks) >> 5;      // even, >= 2 in all modes
  int b0 = 0, b1 = 1;
  for (int tt = 0; tt < nt; tt += 2) {
    const int kc = ks + (tt << 5);
    const int s2 = 3 - b0 - b1;       // the third buffer
    // sub-phase 0: compute tile tt (A in b0, B in bfU)
    {
      const int kst = (kc + 64 < ke) ? kc + 64 : ks;   // A tile tt+2
      STAGE_A(s2, kst);
      LOADB_G(bfV, kc + 32);          // B tile tt+1 (always valid: tt<=nt-2)
      LOADA(b0);
      MMAW(bfU);
      VMC6(); BARW();
    }
    // sub-phase 1: compute tile tt+1 (A in b1, B in bfV)
    {
      const int kst = (kc + 96 < ke) ? kc + 96 : ks;   // A tile tt+3
      const int kb  = (kc + 64 < ke) ? kc + 64 : ks;   // B tile tt+2 (clamped)
      STAGE_A(b0, kst);
      LOADB_G(bfU, kb);
      LOADA(b1);
      MMAW(bfV);
      VMC6(); BARW();
    }
    b1 = b0; b0 = s2;                 // bufs advance by 2 tiles
  }

  // epilogue: C/D layout col=lane&15, row=quad*4+reg [m89-verified]
#pragma unroll
  for (int mi = 0; mi < 8; ++mi) {
#pragma unroll
    for (int ni = 0; ni < 4; ++ni) {
      const int cc = j0 + w * 64 + ni * 16 + lm;
      const float badd = ADDB ? bias[cc] : 0.f;
#pragma unroll
      for (int r = 0; r < 4; ++r) {
        const int rr = i0 + mi * 16 + lq * 4 + r;
        if (OUTMODE == 0)
          ((u16*)Cv)[(size_t)rr * LDC_ + cc] = f2bf(acc[mi][ni][r] * scale + badd);
        else
          atomicAdd((float*)Cv + (size_t)rr * LDC_ + cc, acc[mi][ni][r]);
      }
    }
  }
}

// ---------- row softmax with causal + padding mask (single bf16 input) ----------
__global__ __launch_bounds__(256) void softmax_rows(
    const u16* __restrict__ S0,
    u16* __restrict__ att, const int* __restrict__ npad_p) {
  const int i = blockIdx.x;
  const int np = *npad_p;
  const int kend = ((i >> 7) + 1) << 7;   // 128-rounded: matches attV read range
  const u16* r0 = S0 + (size_t)i * SEQ;
  u16* arow = att + (size_t)i * SEQ;
  const int t = threadIdx.x;

  float m = -3.0e38f, s = 0.f;
  for (int j = np + t; j <= i; j += 256) {
    float v = bf2f(r0[j]);
    if (v > m) { s = s * __expf(m - v) + 1.f; m = v; }
    else       { s += __expf(v - m); }
  }
#pragma unroll
  for (int off = 32; off > 0; off >>= 1) {
    float mo = __shfl_xor(m, off);
    float so = __shfl_xor(s, off);
    float M = fmaxf(m, mo);
    s = s * __expf(m - M) + so * __expf(mo - M);
    m = M;
  }
  __shared__ float sm[4], ss[4];
  const int w = t >> 6, l = t & 63;
  if (l == 0) { sm[w] = m; ss[w] = s; }
  __syncthreads();
  const float M = fmaxf(fmaxf(sm[0], sm[1]), fmaxf(sm[2], sm[3]));
  const float Ssum = ss[0] * __expf(sm[0] - M) + ss[1] * __expf(sm[1] - M) +
                     ss[2] * __expf(sm[2] - M) + ss[3] * __expf(sm[3] - M);
  const float inv = 1.f / Ssum;  // padded rows masked to 0 below; inv unused there

  for (int j0b = t * 8; j0b < kend; j0b += 2048) {
    union { u16 s8[8]; uint4 v; } u;
#pragma unroll
    for (int q = 0; q < 8; ++q) {
      const int j = j0b + q;
      float a = 0.f;
      if (j >= np && j <= i)
        a = __expf(bf2f(r0[j]) - M) * inv;
      u.s8[q] = f2bf(a);
    }
    *(uint4*)(arow + j0b) = u.v;
  }
}

// ---------- launch ----------

extern "C" void kernel_launch(void* const* d_in, const int* in_sizes, int n_in,
                              void* d_out, int out_size, void* d_ws, size_t ws_size,
                              hipStream_t stream) {
  const float* x = (const float*)d_in[0];
  const float* W = (const float*)d_in[1];
  const float* b = (const float*)d_in[2];
  const int* npad = (const int*)d_in[3];
  float* out = (float*)d_out;

  // workspace:
  // [xb 16MB | Wt 24MB] reused as att 32MB ][ qkvb 48MB ][ vt 16MB ][ sc0 32MB ]
  char* p = (char*)d_ws;
  u16* xb = (u16*)p;
  u16* Wt = (u16*)(p + (size_t)SEQ * FEAT * 2);
  u16* att = (u16*)p;
  p += (size_t)SEQ * FEAT * 2 + (size_t)F3 * FEAT * 2;
  u16* qkvb = (u16*)p;  p += (size_t)SEQ * F3 * 2;
  u16* vt   = (u16*)p;  p += (size_t)FEAT * SEQ * 2;
  u16* sc0  = (u16*)p;  p += (size_t)SEQ * SEQ * 2;   // bf16 scores (causal blocks)
  if (ws_size < (size_t)(p - (char*)d_ws)) return;

  const float scale = 0.02209708691207961f;  // 1/sqrt(2048)

  // zero d_out (att@v split-K atomically accumulates into it)
  hipMemsetAsync(d_out, 0, (size_t)SEQ * FEAT * sizeof(float), stream);

  cvt_f32_bf16<<<SEQ * FEAT / 8 / 256, 256, 0, stream>>>(x, xb, SEQ * FEAT / 8);
  transp_f2b<<<dim3(F3 / 32, FEAT / 32), dim3(32, 8), 0, stream>>>(W, F3, Wt, FEAT);
  // qkv = x @ W + b: 128x256 tiles, grid 24x32 = 768 blocks (3 blocks/CU)
  gemmw<FEAT, FEAT, F3, 0, 1, 0, 1><<<dim3(F3 / 256, SEQ / 128), 256, 0, stream>>>(
      xb, Wt, (void*)qkvb, FEAT, b, 1.0f);
  transp_b2b<<<dim3(FEAT / 32, SEQ / 32), dim3(32, 8), 0, stream>>>(
      qkvb + 2 * FEAT, F3, vt, SEQ);
  // scores = (q @ k^T)/sqrt(F): compact triangular grid, 272 blocks
  gemmw<F3, F3, SEQ, 0, 0, 2, 0><<<dim3(272), 256, 0, stream>>>(
      qkvb, qkvb + FEAT, (void*)sc0, FEAT, nullptr, scale);
  softmax_rows<<<SEQ, 256, 0, stream>>>(sc0, att, npad);
  // out = att @ v: causal split-K=2, flat LPT grid (512 blocks, longest-K
  // first), fp32 atomicAdd
  gemmw<SEQ, SEQ, FEAT, 1, 0, 1, 0><<<dim3(512), 256, 0, stream>>>(
      att, vt, (void*)out, 0, nullptr, 1.0f);
}

// Round 6
// 440.506 us; speedup vs baseline: 3.4695x; 3.4695x over previous
//
#include <hip/hip_runtime.h>
#include <cstdint>
#include <cstddef>
#include <cmath>

typedef unsigned short u16;
typedef short v8s __attribute__((ext_vector_type(8)));
typedef float v4f __attribute__((ext_vector_type(4)));

constexpr int SEQ = 4096;
constexpr int FEAT = 2048;
constexpr int F3 = 6144;

// ---------- helpers ----------

__device__ __forceinline__ u16 f2bf(float f) {
  union { float f; uint32_t u; } v; v.f = f;
  uint32_t r = v.u + 0x7FFFu + ((v.u >> 16) & 1u);  // round-to-nearest-even
  return (u16)(r >> 16);
}

__device__ __forceinline__ float bf2f(u16 s) {
  union { uint32_t u; float f; } v; v.u = ((uint32_t)s) << 16;
  return v.f;
}

// async global->LDS, 16B per lane; lds dest is wave-uniform base (HW: base+lane*16)
__device__ __forceinline__ void gld_lds16(const u16* g, u16* l) {
  __builtin_amdgcn_global_load_lds(
      (const __attribute__((address_space(1))) void*)g,
      (__attribute__((address_space(3))) void*)l, 16, 0, 0);
}

// ---------- conversion / transpose ----------

__global__ void cvt_f32_bf16(const float* __restrict__ in, u16* __restrict__ out, int n8) {
  int i = blockIdx.x * 256 + threadIdx.x;
  if (i >= n8) return;
  const float4* p = (const float4*)in + (size_t)i * 2;
  float4 a = p[0], b = p[1];
  union { u16 s[8]; uint4 v; } u;
  u.s[0] = f2bf(a.x); u.s[1] = f2bf(a.y); u.s[2] = f2bf(a.z); u.s[3] = f2bf(a.w);
  u.s[4] = f2bf(b.x); u.s[5] = f2bf(b.y); u.s[6] = f2bf(b.z); u.s[7] = f2bf(b.w);
  *(uint4*)(out + (size_t)i * 8) = u.v;
}

__global__ void transp_f2b(const float* __restrict__ in, int ldin,
                           u16* __restrict__ out, int ldout) {
  __shared__ float tile[32][33];
  int c0 = blockIdx.x * 32, r0 = blockIdx.y * 32;
  int tx = threadIdx.x, ty = threadIdx.y;
#pragma unroll
  for (int p = 0; p < 4; ++p)
    tile[ty + 8 * p][tx] = in[(size_t)(r0 + ty + 8 * p) * ldin + c0 + tx];
  __syncthreads();
#pragma unroll
  for (int p = 0; p < 4; ++p)
    out[(size_t)(c0 + ty + 8 * p) * ldout + r0 + tx] = f2bf(tile[tx][ty + 8 * p]);
}

__global__ void transp_b2b(const u16* __restrict__ in, int ldin,
                           u16* __restrict__ out, int ldout) {
  __shared__ u16 tile[32][33];
  int c0 = blockIdx.x * 32, r0 = blockIdx.y * 32;
  int tx = threadIdx.x, ty = threadIdx.y;
#pragma unroll
  for (int p = 0; p < 4; ++p)
    tile[ty + 8 * p][tx] = in[(size_t)(r0 + ty + 8 * p) * ldin + c0 + tx];
  __syncthreads();
#pragma unroll
  for (int p = 0; p < 4; ++p)
    out[(size_t)(c0 + ty + 8 * p) * ldout + r0 + tx] = tile[tx][ty + 8 * p];
}

// ---------- gemmw: C[M,N] = A[M,K] * B[N,K]^T  (bf16 in, k contiguous) ----------
// Tile 128(M)x256(N), BK=32, 256 thr = 4 waves; each wave owns 128x64.
// B is PRIVATE per wave (disjoint 64-col slices) -> B never touches LDS: it
// loads global->reg in MFMA fragment layout (16B/lane), double-buffered via
// 2x-unrolled loop. A (shared 4-way) stays in LDS, 3-buf rotation (24 KiB).
// r6 FIX vs r5: __launch_bounds__(256, 2). r5's (256,3) capped the unified
// reg file at ~170/wave < the ~218 needed (90 arch + 128 acc) -> ~50-reg
// scratch spill -> 2 GB WRITE_SIZE, 675 us. At (256,2) the budget is 256:
// no spill (r4 proved 100 arch + 128 agpr fits). Occupancy: 2 blocks/CU.
// Phase p (one 32-K tile): STAGE_A(p+2) [2 gld_lds16] | LOADB_G(p+1) [4
//   global dwordx4 -> regs] | LOADA(p) [8 ds_read_b128] | 32 MFMA (B regs
//   loaded last phase) | vmcnt(6) | s_barrier.
// vmcnt-safety: exactly 6 VMEM ops per phase (barriers pin membership) =>
// vmcnt(6) pre-barrier proves A(p+1) (issued phase p-1, older) landed for
// ALL waves after the barrier. B-reg consumption is compiler-waited.
// A-overwrite safety: STAGE_A(p+2) hits the buf read at p-1; those ds_reads
// drained (lgkm before MFMA) before their wave crossed BAR(p-1).
// LDS swizzle (proven, conflicts=0): row of 32 elems = 4 chunks of 16B;
// logical chunk c at physical (c + (row>>1))&3; global source pre-rotated.
// MODE: 0 = rect grid (XCD col-major swizzle if SWZ: same-XCD share B panel);
//       1 = att@v flat LPT grid (512 blocks, longest-K first, fp32 atomicAdd);
//       2 = causal triangular grid (bj <= bi/2) x split-K z=2 (blockIdx.y),
//           DISJOINT bf16 outputs at Cv + z*SEQ*SEQ (r0-proven scheme).

#define BARW() asm volatile("s_barrier" ::: "memory")
#define VMC6() asm volatile("s_waitcnt vmcnt(6)" ::: "memory")

#define STAGE_A(SB, KO) do { \
  u16* Lb = &Aldss[SB][0] + w * 512; \
  gld_lds16(pA0 + (KO), Lb); \
  gld_lds16(pA0 + (size_t)64 * LDA_ + (KO), Lb + 2048); \
} while (0)

#define LOADA(BUF) do { _Pragma("unroll") \
  for (int mi = 0; mi < 8; ++mi) \
    af[mi] = *(const v8s*)(&Aldss[BUF][0] + (mi * 16 + lm) * 32 + lqs); \
} while (0)

#define LOADB_G(DST, KO) do { _Pragma("unroll") \
  for (int ni = 0; ni < 4; ++ni) \
    DST[ni] = *(const v8s*)(pBF + (size_t)(ni * 16) * LDB_ + (KO)); \
} while (0)

#define MMAW(BF) do { \
  __builtin_amdgcn_s_setprio(1); \
  _Pragma("unroll") \
  for (int mi = 0; mi < 8; ++mi) { _Pragma("unroll") \
    for (int ni = 0; ni < 4; ++ni) \
      acc[mi][ni] = __builtin_amdgcn_mfma_f32_16x16x32_bf16(af[mi], BF[ni], acc[mi][ni], 0, 0, 0); } \
  __builtin_amdgcn_s_setprio(0); \
} while (0)

__device__ __forceinline__ int tri_S(int v) {  // #blocks before row-block v
  const int u = v >> 1;
  return (v & 1) ? (u + 1) * (u + 1) : u * u + u;
}

template<int LDA_, int LDB_, int LDC_, int OUTMODE /*0=bf16 store, 1=fp32 atomicAdd*/,
         int ADDB, int MODE, int SWZ>
__global__ __launch_bounds__(256, 2) void gemmw(
    const u16* __restrict__ A, const u16* __restrict__ B,
    void* __restrict__ Cv, int K,
    const float* __restrict__ bias, float scale) {
  int bi, bj, ks, ke;
  if (MODE == 2) {
    // causal triangular grid (272 blocks in x, XCD-chunked) x split-K z=2 (y)
    const int b = blockIdx.x;
    const int cpx = (int)gridDim.x >> 3;
    const int s = (b & 7) * cpx + (b >> 3);
    bi = 2 * (int)sqrtf((float)s);
    while (tri_S(bi + 1) <= s) ++bi;
    while (tri_S(bi) > s) --bi;
    bj = s - tri_S(bi);
    const int half = K >> 1;                     // 1024 -> nt = 32, even
    ks = blockIdx.y * half;  ke = ks + half;
    Cv = (void*)((u16*)Cv + (size_t)blockIdx.y * SEQ * SEQ);  // disjoint buffer
  } else if (MODE == 1) {
    // flat LPT grid: 512 blocks, descending K (longest first)
    const int f = blockIdx.x;
    bi = ((int)gridDim.x >> 4) - 1 - (f >> 4);   // 31..0
    bj = (f >> 1) & 7;
    const int z = f & 1;
    const int kq = (bi + 1) * 64;
    ks = z ? kq : 0;  ke = ks + kq;              // nt = 2*(bi+1), even, >= 2
  } else {
    if (SWZ) {
      // column-major within XCD chunk: same-XCD neighbors share the B panel
      const int gx = gridDim.x, gy = gridDim.y;
      const int b = blockIdx.y * gx + blockIdx.x;
      const int cpx = (gx * gy) >> 3;            // nwg % 8 == 0
      const int s = (b & 7) * cpx + (b >> 3);
      bi = s % gy;  bj = s / gy;
    } else { bj = blockIdx.x; bi = blockIdx.y; }
    ks = 0; ke = K;
  }
  const int i0 = bi * 128, j0 = bj * 256;

  __shared__ u16 Aldss[3][4096];   // 3 bufs x (128 rows x 32 k) = 24 KiB

  const int t = threadIdx.x;
  const int w = t >> 6, l = t & 63;
  const int lm = l & 15, lq = l >> 4;
  // fragment read: physical chunk = (lq + (row>>1)) & 3; row bases are
  // multiples of 8 => (row>>1)&3 == (lm>>1)&3
  const int lqs = ((lq + (lm >> 1)) & 3) * 8;

  // A staging: wave w covers rows [w*16, w*16+16) and +64; lane l: row =
  // base + (l>>2), physical chunk l&3, logical chunk = ((l&3)-((row>>1)&3))&3.
  const int rA = w * 16 + (l >> 2);
  const int cA = ((((l & 3) - ((rA >> 1) & 3)) & 3)) * 8;
  const u16* pA0 = A + (size_t)(i0 + rA) * LDA_ + cA;
  // B direct-to-reg: lane reads 16B at (row = j0 + w*64 + ni*16 + lm, k + lq*8)
  const u16* pBF = B + (size_t)(j0 + w * 64 + lm) * LDB_ + lq * 8;

  v4f acc[8][4];
#pragma unroll
  for (int a = 0; a < 8; ++a)
#pragma unroll
    for (int b2 = 0; b2 < 4; ++b2)
      acc[a][b2] = v4f{0.f, 0.f, 0.f, 0.f};

  v8s af[8], bfU[4], bfV[4];

  // prologue: stage A tiles 0,1; load B tile 0 -> bfU.
  // vmcnt(6) leaves {A(1):2, B(0):4} in flight => A(0) landed.
  STAGE_A(0, ks); STAGE_A(1, ks + 32);
  LOADB_G(bfU, ks);
  VMC6(); BARW();

  const int nt = (ke - ks) >> 5;      // even, >= 2 in all modes
  int b0 = 0, b1 = 1;
  for (int tt = 0; tt < nt; tt += 2) {
    const int kc = ks + (tt << 5);
    const int s2 = 3 - b0 - b1;       // the third buffer
    // sub-phase 0: compute tile tt (A in b0, B in bfU)
    {
      const int kst = (kc + 64 < ke) ? kc + 64 : ks;   // A tile tt+2
      STAGE_A(s2, kst);
      LOADB_G(bfV, kc + 32);          // B tile tt+1 (always valid: tt<=nt-2)
      LOADA(b0);
      MMAW(bfU);
      VMC6(); BARW();
    }
    // sub-phase 1: compute tile tt+1 (A in b1, B in bfV)
    {
      const int kst = (kc + 96 < ke) ? kc + 96 : ks;   // A tile tt+3
      const int kb  = (kc + 64 < ke) ? kc + 64 : ks;   // B tile tt+2 (clamped)
      STAGE_A(b0, kst);
      LOADB_G(bfU, kb);
      LOADA(b1);
      MMAW(bfV);
      VMC6(); BARW();
    }
    b1 = b0; b0 = s2;                 // bufs advance by 2 tiles
  }

  // epilogue: C/D layout col=lane&15, row=quad*4+reg [m89-verified]
#pragma unroll
  for (int mi = 0; mi < 8; ++mi) {
#pragma unroll
    for (int ni = 0; ni < 4; ++ni) {
      const int cc = j0 + w * 64 + ni * 16 + lm;
      const float badd = ADDB ? bias[cc] : 0.f;
#pragma unroll
      for (int r = 0; r < 4; ++r) {
        const int rr = i0 + mi * 16 + lq * 4 + r;
        if (OUTMODE == 0)
          ((u16*)Cv)[(size_t)rr * LDC_ + cc] = f2bf(acc[mi][ni][r] * scale + badd);
        else
          atomicAdd((float*)Cv + (size_t)rr * LDC_ + cc, acc[mi][ni][r]);
      }
    }
  }
}

// ---------- row softmax with causal + padding mask ----------
// scores come as two bf16 split-K partials: s(i,j) = sc0[i,j] + sc1[i,j]
__global__ __launch_bounds__(256) void softmax_rows(
    const u16* __restrict__ S0, const u16* __restrict__ S1,
    u16* __restrict__ att, const int* __restrict__ npad_p) {
  const int i = blockIdx.x;
  const int np = *npad_p;
  const int kend = ((i >> 7) + 1) << 7;   // 128-rounded: matches attV read range
  const u16* r0 = S0 + (size_t)i * SEQ;
  const u16* r1 = S1 + (size_t)i * SEQ;
  u16* arow = att + (size_t)i * SEQ;
  const int t = threadIdx.x;

  float m = -3.0e38f, s = 0.f;
  for (int j = np + t; j <= i; j += 256) {
    float v = bf2f(r0[j]) + bf2f(r1[j]);
    if (v > m) { s = s * __expf(m - v) + 1.f; m = v; }
    else       { s += __expf(v - m); }
  }
#pragma unroll
  for (int off = 32; off > 0; off >>= 1) {
    float mo = __shfl_xor(m, off);
    float so = __shfl_xor(s, off);
    float M = fmaxf(m, mo);
    s = s * __expf(m - M) + so * __expf(mo - M);
    m = M;
  }
  __shared__ float sm[4], ss[4];
  const int w = t >> 6, l = t & 63;
  if (l == 0) { sm[w] = m; ss[w] = s; }
  __syncthreads();
  const float M = fmaxf(fmaxf(sm[0], sm[1]), fmaxf(sm[2], sm[3]));
  const float Ssum = ss[0] * __expf(sm[0] - M) + ss[1] * __expf(sm[1] - M) +
                     ss[2] * __expf(sm[2] - M) + ss[3] * __expf(sm[3] - M);
  const float inv = 1.f / Ssum;  // padded rows masked to 0 below; inv unused there

  for (int j0b = t * 8; j0b < kend; j0b += 2048) {
    union { u16 s8[8]; uint4 v; } u;
#pragma unroll
    for (int q = 0; q < 8; ++q) {
      const int j = j0b + q;
      float a = 0.f;
      if (j >= np && j <= i)
        a = __expf(bf2f(r0[j]) + bf2f(r1[j]) - M) * inv;
      u.s8[q] = f2bf(a);
    }
    *(uint4*)(arow + j0b) = u.v;
  }
}

// ---------- launch ----------

extern "C" void kernel_launch(void* const* d_in, const int* in_sizes, int n_in,
                              void* d_out, int out_size, void* d_ws, size_t ws_size,
                              hipStream_t stream) {
  const float* x = (const float*)d_in[0];
  const float* W = (const float*)d_in[1];
  const float* b = (const float*)d_in[2];
  const int* npad = (const int*)d_in[3];
  float* out = (float*)d_out;

  // workspace (168 MB):
  // [xb 16MB | Wt 24MB] reused as att 32MB ][ qkvb 48MB ][ vt 16MB ][ sc0 32MB | sc1 32MB ]
  char* p = (char*)d_ws;
  u16* xb = (u16*)p;
  u16* Wt = (u16*)(p + (size_t)SEQ * FEAT * 2);
  u16* att = (u16*)p;
  p += (size_t)SEQ * FEAT * 2 + (size_t)F3 * FEAT * 2;
  u16* qkvb = (u16*)p;  p += (size_t)SEQ * F3 * 2;
  u16* vt   = (u16*)p;  p += (size_t)FEAT * SEQ * 2;
  u16* sc0  = (u16*)p;  p += (size_t)SEQ * SEQ * 2;   // bf16 split-K partial 0
  u16* sc1  = (u16*)p;  p += (size_t)SEQ * SEQ * 2;   // bf16 split-K partial 1
  if (ws_size < (size_t)(p - (char*)d_ws)) return;

  const float scale = 0.02209708691207961f;  // 1/sqrt(2048)

  // zero d_out (att@v split-K atomically accumulates into it)
  hipMemsetAsync(d_out, 0, (size_t)SEQ * FEAT * sizeof(float), stream);

  cvt_f32_bf16<<<SEQ * FEAT / 8 / 256, 256, 0, stream>>>(x, xb, SEQ * FEAT / 8);
  transp_f2b<<<dim3(F3 / 32, FEAT / 32), dim3(32, 8), 0, stream>>>(W, F3, Wt, FEAT);
  // qkv = x @ W + b: 128x256 tiles, grid 24x32 = 768 blocks (2 blocks/CU)
  gemmw<FEAT, FEAT, F3, 0, 1, 0, 1><<<dim3(F3 / 256, SEQ / 128), 256, 0, stream>>>(
      xb, Wt, (void*)qkvb, FEAT, b, 1.0f);
  transp_b2b<<<dim3(FEAT / 32, SEQ / 32), dim3(32, 8), 0, stream>>>(
      qkvb + 2 * FEAT, F3, vt, SEQ);
  // scores = (q @ k^T)/sqrt(F): triangular grid (272) x split-K z=2 -> sc0/sc1
  gemmw<F3, F3, SEQ, 0, 0, 2, 0><<<dim3(272, 2), 256, 0, stream>>>(
      qkvb, qkvb + FEAT, (void*)sc0, FEAT, nullptr, scale);
  softmax_rows<<<SEQ, 256, 0, stream>>>(sc0, sc1, att, npad);
  // out = att @ v: causal split-K=2, flat LPT grid (512 blocks, longest-K
  // first), fp32 atomicAdd
  gemmw<SEQ, SEQ, FEAT, 1, 0, 1, 0><<<dim3(512), 256, 0, stream>>>(
      att, vt, (void*)out, 0, nullptr, 1.0f);
}

// Round 7
// 393.238 us; speedup vs baseline: 3.8865x; 1.1202x over previous
//
#include <hip/hip_runtime.h>
#include <cstdint>
#include <cstddef>
#include <cmath>

typedef unsigned short u16;
typedef short v8s __attribute__((ext_vector_type(8)));
typedef float v4f __attribute__((ext_vector_type(4)));

constexpr int SEQ = 4096;
constexpr int FEAT = 2048;
constexpr int F3 = 6144;

// ---------- helpers ----------

__device__ __forceinline__ u16 f2bf(float f) {
  union { float f; uint32_t u; } v; v.f = f;
  uint32_t r = v.u + 0x7FFFu + ((v.u >> 16) & 1u);  // round-to-nearest-even
  return (u16)(r >> 16);
}

__device__ __forceinline__ float bf2f(u16 s) {
  union { uint32_t u; float f; } v; v.u = ((uint32_t)s) << 16;
  return v.f;
}

// async global->LDS, 16B per lane; lds dest is wave-uniform base (HW: base+lane*16)
__device__ __forceinline__ void gld_lds16(const u16* g, u16* l) {
  __builtin_amdgcn_global_load_lds(
      (const __attribute__((address_space(1))) void*)g,
      (__attribute__((address_space(3))) void*)l, 16, 0, 0);
}

// ---------- conversion / transpose ----------

__global__ void cvt_f32_bf16(const float* __restrict__ in, u16* __restrict__ out, int n8) {
  int i = blockIdx.x * 256 + threadIdx.x;
  if (i >= n8) return;
  const float4* p = (const float4*)in + (size_t)i * 2;
  float4 a = p[0], b = p[1];
  union { u16 s[8]; uint4 v; } u;
  u.s[0] = f2bf(a.x); u.s[1] = f2bf(a.y); u.s[2] = f2bf(a.z); u.s[3] = f2bf(a.w);
  u.s[4] = f2bf(b.x); u.s[5] = f2bf(b.y); u.s[6] = f2bf(b.z); u.s[7] = f2bf(b.w);
  *(uint4*)(out + (size_t)i * 8) = u.v;
}

__global__ void transp_f2b(const float* __restrict__ in, int ldin,
                           u16* __restrict__ out, int ldout) {
  __shared__ float tile[32][33];
  int c0 = blockIdx.x * 32, r0 = blockIdx.y * 32;
  int tx = threadIdx.x, ty = threadIdx.y;
#pragma unroll
  for (int p = 0; p < 4; ++p)
    tile[ty + 8 * p][tx] = in[(size_t)(r0 + ty + 8 * p) * ldin + c0 + tx];
  __syncthreads();
#pragma unroll
  for (int p = 0; p < 4; ++p)
    out[(size_t)(c0 + ty + 8 * p) * ldout + r0 + tx] = f2bf(tile[tx][ty + 8 * p]);
}

__global__ void transp_b2b(const u16* __restrict__ in, int ldin,
                           u16* __restrict__ out, int ldout) {
  __shared__ u16 tile[32][33];
  int c0 = blockIdx.x * 32, r0 = blockIdx.y * 32;
  int tx = threadIdx.x, ty = threadIdx.y;
#pragma unroll
  for (int p = 0; p < 4; ++p)
    tile[ty + 8 * p][tx] = in[(size_t)(r0 + ty + 8 * p) * ldin + c0 + tx];
  __syncthreads();
#pragma unroll
  for (int p = 0; p < 4; ++p)
    out[(size_t)(c0 + ty + 8 * p) * ldout + r0 + tx] = tile[tx][ty + 8 * p];
}

// ---------- gemmw: C[M,N] = A[M,K] * B[N,K]^T  (bf16 in, k contiguous) ----------
// r4-proven structure (115 us on GEMM1, 896 TF). Tile 128(M)x256(N), BK=32,
// 256 thr = 4 waves; each wave owns 128x64 (reuse 42.7 FLOP/LDS-byte).
// LDS: single region [buf][A 128x32 | B 256x32] = 24 KiB x 3 bufs = 72 KiB
// -> 2 blocks/CU (8 waves), __launch_bounds__(256,2).
// Phase (one 32-K tile): STAGE(t+2, 6 gld_lds16/thread) | LOADA (8 ds) |
//   32 MFMA (bf preloaded) | vmcnt(6) | s_barrier | LOADB(t+1)->regs.
// Race-safety (verified r3/r4): vmcnt(6) pre-barrier leaves only this
// phase's 6 stages in flight => post-barrier, tile t+1 fully in LDS for all
// waves; STAGE(t+2) overwrites tile t-1's buffer whose last reads drained
// before their wave crossed BAR(t-1).
// LDS swizzle (proven, conflicts=0): row of 32 elems = 4 chunks of 16B;
// logical chunk c at physical (c + (row>>1))&3; global source pre-rotated.
// MODE: 0 = rect grid (XCD col-major swizzle if SWZ: same-XCD share B panel);
//       1 = att@v flat LPT grid (512 blocks, longest-K first, fp32 atomicAdd).

#define BARW() asm volatile("s_barrier" ::: "memory")
#define VMC6() asm volatile("s_waitcnt vmcnt(6)" ::: "memory")
#define LGKM0() asm volatile("s_waitcnt lgkmcnt(0)" ::: "memory")

#define STAGE(SB, KO) do { \
  u16* Lb = &LDSU[SB][0] + w * 512; \
  gld_lds16(pA0 + (KO), Lb); \
  gld_lds16(pA0 + (size_t)64 * LDA_ + (KO), Lb + 2048); \
  gld_lds16(pB0 + (KO), Lb + 4096); \
  gld_lds16(pB0 + (size_t)64 * LDB_ + (KO), Lb + 4096 + 2048); \
  gld_lds16(pB0 + (size_t)128 * LDB_ + (KO), Lb + 4096 + 4096); \
  gld_lds16(pB0 + (size_t)192 * LDB_ + (KO), Lb + 4096 + 6144); \
} while (0)

#define LOADA(BUF) do { _Pragma("unroll") \
  for (int mi = 0; mi < 8; ++mi) \
    af[mi] = *(const v8s*)(&LDSU[BUF][0] + (mi * 16 + lm) * 32 + lqs); \
} while (0)

#define LOADB(BUF) do { _Pragma("unroll") \
  for (int ni = 0; ni < 4; ++ni) \
    bf4[ni] = *(const v8s*)(&LDSU[BUF][0] + 4096 + (w * 64 + ni * 16 + lm) * 32 + lqs); \
} while (0)

template<int LDA_, int LDB_, int LDC_, int OUTMODE /*0=bf16 store, 1=fp32 atomicAdd*/,
         int ADDB, int MODE, int SWZ>
__global__ __launch_bounds__(256, 2) void gemmw(
    const u16* __restrict__ A, const u16* __restrict__ B,
    void* __restrict__ Cv, int K,
    const float* __restrict__ bias, float scale) {
  int bi, bj, ks, ke;
  if (MODE == 1) {
    // flat LPT grid: 512 blocks, descending K (longest first)
    const int f = blockIdx.x;
    bi = ((int)gridDim.x >> 4) - 1 - (f >> 4);   // 31..0
    bj = (f >> 1) & 7;
    const int z = f & 1;
    const int kq = (bi + 1) * 64;
    ks = z ? kq : 0;  ke = ks + kq;              // nt = 2*(bi+1), even, >= 2
  } else {
    if (SWZ) {
      // column-major within XCD chunk: same-XCD neighbors share the B panel
      const int gx = gridDim.x, gy = gridDim.y;
      const int b = blockIdx.y * gx + blockIdx.x;
      const int cpx = (gx * gy) >> 3;            // nwg % 8 == 0
      const int s = (b & 7) * cpx + (b >> 3);
      bi = s % gy;  bj = s / gy;
    } else { bj = blockIdx.x; bi = blockIdx.y; }
    ks = 0; ke = K;
  }
  const int i0 = bi * 128, j0 = bj * 256;

  // [buf][ A: 128 rows x 32 (4096 elems) | B: 256 rows x 32 (8192 elems) ]
  __shared__ u16 LDSU[3][12288];   // 72 KiB

  const int t = threadIdx.x;
  const int w = t >> 6, l = t & 63;
  const int lm = l & 15, lq = l >> 4;
  // fragment read: physical chunk = (lq + (row>>1)) & 3; row bases are
  // multiples of 8 => (row>>1)&3 == (lm>>1)&3
  const int lqs = ((lq + (lm >> 1)) & 3) * 8;

  // staging: wave w handles instrs covering 16-row groups; lane l: row =
  // base + (l>>2), physical chunk l&3, logical = ((l&3)-((row>>1)&3))&3.
  const int rA = w * 16 + (l >> 2);
  const int cA = ((((l & 3) - ((rA >> 1) & 3)) & 3)) * 8;
  const u16* pA0 = A + (size_t)(i0 + rA) * LDA_ + cA;
  const u16* pB0 = B + (size_t)(j0 + rA) * LDB_ + cA;

  v4f acc[8][4];
#pragma unroll
  for (int a = 0; a < 8; ++a)
#pragma unroll
    for (int b2 = 0; b2 < 4; ++b2)
      acc[a][b2] = v4f{0.f, 0.f, 0.f, 0.f};

  v8s af[8], bf4[4];

  // prologue: stage tiles 0 (buf0) and 1 (buf1); vmcnt(6) -> tile0 landed
  STAGE(0, ks); STAGE(1, ks + 32);
  VMC6(); BARW();
  LOADB(0);                           // B fragments of tile 0 -> regs

  const int nt = (ke - ks) >> 5;      // even, >= 2 in all modes
  int b0 = 0, b1 = 1;
  for (int tt = 0; tt < nt; tt += 2) {
    const int kc = ks + (tt << 5);
    const int s2 = 3 - b0 - b1;       // the third buffer
    // sub-phase 0: compute tile tt (A in b0, B in bfU=bf4 preloaded)
    {
      const int kst = (kc + 64 < ke) ? kc + 64 : ks;   // A+B tile tt+2
      STAGE(s2, kst);
      LOADA(b0);
      __builtin_amdgcn_s_setprio(1);
#pragma unroll
      for (int mi = 0; mi < 8; ++mi)
#pragma unroll
        for (int ni = 0; ni < 4; ++ni)
          acc[mi][ni] = __builtin_amdgcn_mfma_f32_16x16x32_bf16(af[mi], bf4[ni], acc[mi][ni], 0, 0, 0);
      __builtin_amdgcn_s_setprio(0);
      VMC6(); BARW();                 // tile tt+1 landed (all waves)
      LOADB(b1);                      // B fragments of tile tt+1 -> regs
    }
    // sub-phase 1: compute tile tt+1 (A in b1)
    {
      const int kst = (kc + 96 < ke) ? kc + 96 : ks;   // tile tt+3 (clamped)
      STAGE(b0, kst);
      LOADA(b1);
      __builtin_amdgcn_s_setprio(1);
#pragma unroll
      for (int mi = 0; mi < 8; ++mi)
#pragma unroll
        for (int ni = 0; ni < 4; ++ni)
          acc[mi][ni] = __builtin_amdgcn_mfma_f32_16x16x32_bf16(af[mi], bf4[ni], acc[mi][ni], 0, 0, 0);
      __builtin_amdgcn_s_setprio(0);
      VMC6(); BARW();                 // tile tt+2 landed
      LOADB(s2);                      // B fragments of tile tt+2 -> regs
    }
    b1 = b0; b0 = s2;                 // bufs advance by 2 tiles
  }

  // epilogue: C/D layout col=lane&15, row=quad*4+reg [m89-verified]
#pragma unroll
  for (int mi = 0; mi < 8; ++mi) {
#pragma unroll
    for (int ni = 0; ni < 4; ++ni) {
      const int cc = j0 + w * 64 + ni * 16 + lm;
      const float badd = ADDB ? bias[cc] : 0.f;
#pragma unroll
      for (int r = 0; r < 4; ++r) {
        const int rr = i0 + mi * 16 + lq * 4 + r;
        if (OUTMODE == 0)
          ((u16*)Cv)[(size_t)rr * LDC_ + cc] = f2bf(acc[mi][ni][r] * scale + badd);
        else
          atomicAdd((float*)Cv + (size_t)rr * LDC_ + cc, acc[mi][ni][r]);
      }
    }
  }
}

#undef STAGE
#undef LOADA
#undef LOADB

// ---------- gemm8tri: 256x256 8-phase GEMM on a flat triangular grid ----------
// r1-verified schedule (passed, conflicts=0, steady ~1050 TF) deployed where
// its 1-block/CU occupancy is free: GEMM2's 136-block grid (0.53 rounds ->
// makespan = ONE block-time vs gemmw's full-depth round).
// C[M,N] = A[M,K]*B[N,K]^T, bf16, 512 thr = 8 waves (2Mx4N), wave owns 128x64,
// BK=64, double-buffered LDS 128 KiB, K % 128 == 0.
// Per K-tile: 4 quadrant phases; 1 half-tile (2 x gld_lds16) staged per phase;
// counted vmcnt(6) ONLY at phases 4/8; raw s_barrier (no drain).
// LDS swizzle: row of 64 elems = 8 chunks of 16B, logical chunk c at physical
// (c + row) & 7; global source pre-rotated (both-sides rule).
// Stage legality (r1-verified): each stage issues only after the barrier
// following its LDS region's last read (B consumed to regs entirely at P1/P5).

#define LDA8(BUF, MH) do { _Pragma("unroll") \
  for (int fi = 0; fi < 4; ++fi) { \
    const u16* ap = &As8[BUF][wr][(MH) * 4096 + fi * 1024]; \
    af[fi][0] = *(const v8s*)(ap + off0); \
    af[fi][1] = *(const v8s*)(ap + off1); \
  } } while (0)

#define LDB8(BUF) do { _Pragma("unroll") \
  for (int ni = 0; ni < 4; ++ni) { \
    const u16* bp = &Bs8[BUF][bh][bo + ni * 1024]; \
    bfr[ni][0] = *(const v8s*)(bp + off0); \
    bfr[ni][1] = *(const v8s*)(bp + off1); \
  } } while (0)

#define MMA8(MH, NL) do { _Pragma("unroll") \
  for (int fi = 0; fi < 4; ++fi) { _Pragma("unroll") \
    for (int nn = 0; nn < 2; ++nn) { \
      acc[(MH)*4+fi][(NL)+nn] = __builtin_amdgcn_mfma_f32_16x16x32_bf16( \
          af[fi][0], bfr[(NL)+nn][0], acc[(MH)*4+fi][(NL)+nn], 0, 0, 0); \
      acc[(MH)*4+fi][(NL)+nn] = __builtin_amdgcn_mfma_f32_16x16x32_bf16( \
          af[fi][1], bfr[(NL)+nn][1], acc[(MH)*4+fi][(NL)+nn], 0, 0, 0); \
    } } } while (0)

#define STG8A(BUF, H, KO) do { \
  gld_lds16(Ag + (size_t)(H) * 128 * LDA_ + (KO), &As8[BUF][H][w8 * 1024]); \
  gld_lds16(Ag + ((size_t)(H) * 128 + 8) * LDA_ + (KO), &As8[BUF][H][w8 * 1024 + 512]); \
  } while (0)

#define STG8B(BUF, H, KO) do { \
  gld_lds16(Bg + (size_t)(H) * 128 * LDB_ + (KO), &Bs8[BUF][H][w8 * 1024]); \
  gld_lds16(Bg + ((size_t)(H) * 128 + 8) * LDB_ + (KO), &Bs8[BUF][H][w8 * 1024 + 512]); \
  } while (0)

template<int LDA_, int LDB_, int LDC_>
__global__ __launch_bounds__(512, 2) void gemm8tri(
    const u16* __restrict__ A, const u16* __restrict__ B,
    u16* __restrict__ C, int K, float scale) {
  // flat lower-triangular grid (bj <= bi), XCD-chunked; gridDim.x % 8 == 0
  const int b = blockIdx.x;
  const int cpx = (int)gridDim.x >> 3;
  const int s = (b & 7) * cpx + (b >> 3);
  int bi = (int)((sqrtf(8.f * s + 1.f) - 1.f) * 0.5f);
  while ((bi + 1) * (bi + 2) / 2 <= s) ++bi;
  while (bi * (bi + 1) / 2 > s) --bi;
  const int bj = s - bi * (bi + 1) / 2;
  const int i0 = bi * 256, j0 = bj * 256;

  __shared__ u16 As8[2][2][8192];  // [buf][half][128*64], 64 KiB
  __shared__ u16 Bs8[2][2][8192];  // 64 KiB

  const int t = threadIdx.x;
  const int w8 = t >> 6, l = t & 63;
  const int wr = w8 >> 2, wc = w8 & 3;
  const int lm = l & 15, lq = l >> 4;
  const int bh = wc >> 1, bo = (wc & 1) * 4096;

  // fragment-read offsets within a half (chunk rotation, conflicts=0 r1)
  const int off0 = lm * 64 + ((lq + lm) & 7) * 8;        // s=0
  const int off1 = lm * 64 + ((lq + lm + 4) & 7) * 8;    // s=1

  // staging: row = w8*16 + (l>>3); logical col chunk = ((l&7) - (l>>3)) & 7
  const int srow = w8 * 16 + (l >> 3);
  const int scol = (((l & 7) - (l >> 3)) & 7) * 8;
  const u16* Ag = A + (size_t)(i0 + srow) * LDA_ + scol;
  const u16* Bg = B + (size_t)(j0 + srow) * LDB_ + scol;

  v4f acc[8][4];
#pragma unroll
  for (int a = 0; a < 8; ++a)
#pragma unroll
    for (int b2 = 0; b2 < 4; ++b2)
      acc[a][b2] = v4f{0.f, 0.f, 0.f, 0.f};

  v8s af[4][2], bfr[4][2];

  // prologue: tile0 -> buf0 (B0,B1,A0,A1), tile1 -> buf1 (B0,B1,A0).
  // 14 loads; vmcnt(6) -> oldest 8 (all of buf0) landed.
  STG8B(0, 0, 0); STG8B(0, 1, 0); STG8A(0, 0, 0); STG8A(0, 1, 0);
  STG8B(1, 0, 64); STG8B(1, 1, 64); STG8A(1, 0, 64);
  VMC6(); BARW();

  const int nit = K >> 7;  // K % 128 == 0
  for (int it = 0; it < nit; ++it) {
    const int kc = it << 7;
    const int k1 = kc + 64;                     // tile 2it+1 (always valid)
    int k2 = kc + 128; if (k2 >= K) k2 = 0;     // clamped stages never read
    int k3 = kc + 192; if (k3 >= K) k3 = 0;

    // P1: Q(m0, n0..1) on buf0
    LDA8(0, 0); LDB8(0);
    STG8A(1, 1, k1);
    BARW(); LGKM0();
    __builtin_amdgcn_s_setprio(1); MMA8(0, 0); __builtin_amdgcn_s_setprio(0);
    BARW();
    // P2: Q(m0, n2..3)
    STG8B(0, 0, k2);
    BARW();
    __builtin_amdgcn_s_setprio(1); MMA8(0, 2); __builtin_amdgcn_s_setprio(0);
    BARW();
    // P3: Q(m1, n0..1)
    LDA8(0, 1);
    STG8B(0, 1, k2);
    BARW(); LGKM0();
    __builtin_amdgcn_s_setprio(1); MMA8(1, 0); __builtin_amdgcn_s_setprio(0);
    BARW();
    // P4: Q(m1, n2..3); counted wait -> buf1 fully landed before P5
    STG8A(0, 0, k2);
    BARW();
    __builtin_amdgcn_s_setprio(1); MMA8(1, 2); __builtin_amdgcn_s_setprio(0);
    VMC6(); BARW();
    // P5: Q(m0, n0..1) on buf1
    LDA8(1, 0); LDB8(1);
    STG8A(0, 1, k2);
    BARW(); LGKM0();
    __builtin_amdgcn_s_setprio(1); MMA8(0, 0); __builtin_amdgcn_s_setprio(0);
    BARW();
    // P6: Q(m0, n2..3)
    STG8B(1, 0, k3);
    BARW();
    __builtin_amdgcn_s_setprio(1); MMA8(0, 2); __builtin_amdgcn_s_setprio(0);
    BARW();
    // P7: Q(m1, n0..1)
    LDA8(1, 1);
    STG8B(1, 1, k3);
    BARW(); LGKM0();
    __builtin_amdgcn_s_setprio(1); MMA8(1, 0); __builtin_amdgcn_s_setprio(0);
    BARW();
    // P8: Q(m1, n2..3); counted wait -> buf0 fully landed before next P1
    STG8A(1, 0, k3);
    BARW();
    __builtin_amdgcn_s_setprio(1); MMA8(1, 2); __builtin_amdgcn_s_setprio(0);
    VMC6(); BARW();
  }

  // epilogue: C/D layout col=lane&15, row=quad*4+reg [m89-verified]
#pragma unroll
  for (int mi = 0; mi < 8; ++mi) {
#pragma unroll
    for (int ni = 0; ni < 4; ++ni) {
      const int cc = j0 + wc * 64 + ni * 16 + lm;
#pragma unroll
      for (int r = 0; r < 4; ++r) {
        const int rr = i0 + wr * 128 + mi * 16 + lq * 4 + r;
        C[(size_t)rr * LDC_ + cc] = f2bf(acc[mi][ni][r] * scale);
      }
    }
  }
}

#undef LDA8
#undef LDB8
#undef MMA8
#undef STG8A
#undef STG8B

// ---------- row softmax with causal + padding mask (single bf16 input) ----------
__global__ __launch_bounds__(256) void softmax_rows(
    const u16* __restrict__ S0,
    u16* __restrict__ att, const int* __restrict__ npad_p) {
  const int i = blockIdx.x;
  const int np = *npad_p;
  const int kend = ((i >> 7) + 1) << 7;   // 128-rounded: matches attV read range
  const u16* r0 = S0 + (size_t)i * SEQ;
  u16* arow = att + (size_t)i * SEQ;
  const int t = threadIdx.x;

  float m = -3.0e38f, s = 0.f;
  for (int j = np + t; j <= i; j += 256) {
    float v = bf2f(r0[j]);
    if (v > m) { s = s * __expf(m - v) + 1.f; m = v; }
    else       { s += __expf(v - m); }
  }
#pragma unroll
  for (int off = 32; off > 0; off >>= 1) {
    float mo = __shfl_xor(m, off);
    float so = __shfl_xor(s, off);
    float M = fmaxf(m, mo);
    s = s * __expf(m - M) + so * __expf(mo - M);
    m = M;
  }
  __shared__ float sm[4], ss[4];
  const int w = t >> 6, l = t & 63;
  if (l == 0) { sm[w] = m; ss[w] = s; }
  __syncthreads();
  const float M = fmaxf(fmaxf(sm[0], sm[1]), fmaxf(sm[2], sm[3]));
  const float Ssum = ss[0] * __expf(sm[0] - M) + ss[1] * __expf(sm[1] - M) +
                     ss[2] * __expf(sm[2] - M) + ss[3] * __expf(sm[3] - M);
  const float inv = 1.f / Ssum;  // padded rows masked to 0 below; inv unused there

  for (int j0b = t * 8; j0b < kend; j0b += 2048) {
    union { u16 s8[8]; uint4 v; } u;
#pragma unroll
    for (int q = 0; q < 8; ++q) {
      const int j = j0b + q;
      float a = 0.f;
      if (j >= np && j <= i)
        a = __expf(bf2f(r0[j]) - M) * inv;
      u.s8[q] = f2bf(a);
    }
    *(uint4*)(arow + j0b) = u.v;
  }
}

// ---------- launch ----------

extern "C" void kernel_launch(void* const* d_in, const int* in_sizes, int n_in,
                              void* d_out, int out_size, void* d_ws, size_t ws_size,
                              hipStream_t stream) {
  const float* x = (const float*)d_in[0];
  const float* W = (const float*)d_in[1];
  const float* b = (const float*)d_in[2];
  const int* npad = (const int*)d_in[3];
  float* out = (float*)d_out;

  // workspace:
  // [xb 16MB | Wt 24MB] reused as att 32MB ][ qkvb 48MB ][ vt 16MB ][ sc0 32MB ]
  char* p = (char*)d_ws;
  u16* xb = (u16*)p;
  u16* Wt = (u16*)(p + (size_t)SEQ * FEAT * 2);
  u16* att = (u16*)p;
  p += (size_t)SEQ * FEAT * 2 + (size_t)F3 * FEAT * 2;
  u16* qkvb = (u16*)p;  p += (size_t)SEQ * F3 * 2;
  u16* vt   = (u16*)p;  p += (size_t)FEAT * SEQ * 2;
  u16* sc0  = (u16*)p;  p += (size_t)SEQ * SEQ * 2;   // bf16 scores (causal blocks)
  if (ws_size < (size_t)(p - (char*)d_ws)) return;

  const float scale = 0.02209708691207961f;  // 1/sqrt(2048)

  // zero d_out (att@v split-K atomically accumulates into it)
  hipMemsetAsync(d_out, 0, (size_t)SEQ * FEAT * sizeof(float), stream);

  cvt_f32_bf16<<<SEQ * FEAT / 8 / 256, 256, 0, stream>>>(x, xb, SEQ * FEAT / 8);
  transp_f2b<<<dim3(F3 / 32, FEAT / 32), dim3(32, 8), 0, stream>>>(W, F3, Wt, FEAT);
  // qkv = x @ W + b: 128x256 tiles, grid 24x32 = 768 blocks (2 blocks/CU)
  gemmw<FEAT, FEAT, F3, 0, 1, 0, 1><<<dim3(F3 / 256, SEQ / 128), 256, 0, stream>>>(
      xb, Wt, (void*)qkvb, FEAT, b, 1.0f);
  transp_b2b<<<dim3(FEAT / 32, SEQ / 32), dim3(32, 8), 0, stream>>>(
      qkvb + 2 * FEAT, F3, vt, SEQ);
  // scores = (q @ k^T)/sqrt(F): 8-phase 256^2, flat triangular grid 16*17/2 =
  // 136 blocks (1 block/CU, 0.53 rounds -> makespan = one block-time)
  gemm8tri<F3, F3, SEQ><<<dim3(136), 512, 0, stream>>>(
      qkvb, qkvb + FEAT, sc0, FEAT, scale);
  softmax_rows<<<SEQ, 256, 0, stream>>>(sc0, att, npad);
  // out = att @ v: causal split-K=2, flat LPT grid (512 blocks, longest-K
  // first), fp32 atomicAdd
  gemmw<SEQ, SEQ, FEAT, 1, 0, 1, 0><<<dim3(512), 256, 0, stream>>>(
      att, vt, (void*)out, 0, nullptr, 1.0f);
}

// Round 9
// 375.684 us; speedup vs baseline: 4.0681x; 1.0467x over previous
//
#include <hip/hip_runtime.h>
#include <cstdint>
#include <cstddef>
#include <cmath>

typedef unsigned short u16;
typedef short v8s __attribute__((ext_vector_type(8)));
typedef float v4f __attribute__((ext_vector_type(4)));

constexpr int SEQ = 4096;
constexpr int FEAT = 2048;
constexpr int F3 = 6144;

// ---------- helpers ----------

__device__ __forceinline__ u16 f2bf(float f) {
  union { float f; uint32_t u; } v; v.f = f;
  uint32_t r = v.u + 0x7FFFu + ((v.u >> 16) & 1u);  // round-to-nearest-even
  return (u16)(r >> 16);
}

__device__ __forceinline__ float bf2f(u16 s) {
  union { uint32_t u; float f; } v; v.u = ((uint32_t)s) << 16;
  return v.f;
}

// async global->LDS, 16B per lane; lds dest is wave-uniform base (HW: base+lane*16)
__device__ __forceinline__ void gld_lds16(const u16* g, u16* l) {
  __builtin_amdgcn_global_load_lds(
      (const __attribute__((address_space(1))) void*)g,
      (__attribute__((address_space(3))) void*)l, 16, 0, 0);
}

// ---------- conversion / transpose / combine ----------

__global__ void cvt_f32_bf16(const float* __restrict__ in, u16* __restrict__ out, int n8) {
  int i = blockIdx.x * 256 + threadIdx.x;
  if (i >= n8) return;
  const float4* p = (const float4*)in + (size_t)i * 2;
  float4 a = p[0], b = p[1];
  union { u16 s[8]; uint4 v; } u;
  u.s[0] = f2bf(a.x); u.s[1] = f2bf(a.y); u.s[2] = f2bf(a.z); u.s[3] = f2bf(a.w);
  u.s[4] = f2bf(b.x); u.s[5] = f2bf(b.y); u.s[6] = f2bf(b.z); u.s[7] = f2bf(b.w);
  *(uint4*)(out + (size_t)i * 8) = u.v;
}

__global__ void transp_f2b(const float* __restrict__ in, int ldin,
                           u16* __restrict__ out, int ldout) {
  __shared__ float tile[32][33];
  int c0 = blockIdx.x * 32, r0 = blockIdx.y * 32;
  int tx = threadIdx.x, ty = threadIdx.y;
#pragma unroll
  for (int p = 0; p < 4; ++p)
    tile[ty + 8 * p][tx] = in[(size_t)(r0 + ty + 8 * p) * ldin + c0 + tx];
  __syncthreads();
#pragma unroll
  for (int p = 0; p < 4; ++p)
    out[(size_t)(c0 + ty + 8 * p) * ldout + r0 + tx] = f2bf(tile[tx][ty + 8 * p]);
}

__global__ void transp_b2b(const u16* __restrict__ in, int ldin,
                           u16* __restrict__ out, int ldout) {
  __shared__ u16 tile[32][33];
  int c0 = blockIdx.x * 32, r0 = blockIdx.y * 32;
  int tx = threadIdx.x, ty = threadIdx.y;
#pragma unroll
  for (int p = 0; p < 4; ++p)
    tile[ty + 8 * p][tx] = in[(size_t)(r0 + ty + 8 * p) * ldin + c0 + tx];
  __syncthreads();
#pragma unroll
  for (int p = 0; p < 4; ++p)
    out[(size_t)(c0 + ty + 8 * p) * ldout + r0 + tx] = tile[tx][ty + 8 * p];
}

// out = a + b (fp32, float4-vectorized): combines att@v split-K partials
__global__ __launch_bounds__(256) void add2_f32(
    const float* __restrict__ a, const float* __restrict__ b,
    float* __restrict__ o, int n4) {
  int i = blockIdx.x * 256 + threadIdx.x;
  if (i >= n4) return;
  float4 x = ((const float4*)a)[i], y = ((const float4*)b)[i];
  x.x += y.x; x.y += y.y; x.z += y.z; x.w += y.w;
  ((float4*)o)[i] = x;
}

// ---------- gemmw: C[M,N] = A[M,K] * B[N,K]^T  (bf16 in, k contiguous) ----------
// r4-proven structure (~113 us on GEMM1, ~910 TF). Tile 128(M)x256(N), BK=32,
// 256 thr = 4 waves; each wave owns 128x64 (reuse 42.7 FLOP/LDS-byte).
// LDS: single region [buf][A 128x32 | B 256x32] = 24 KiB x 3 bufs = 72 KiB
// -> 2 blocks/CU (8 waves), __launch_bounds__(256,2).
// Phase (one 32-K tile): STAGE(t+2, 6 gld_lds16/thread) | LOADA (8 ds) |
//   32 MFMA (bf preloaded) | vmcnt(6) | s_barrier | LOADB(t+1)->regs.
// Race-safety (verified r3/r4): vmcnt(6) pre-barrier leaves only this
// phase's 6 stages in flight => post-barrier, tile t+1 fully in LDS for all
// waves; STAGE(t+2) overwrites tile t-1's buffer whose last reads drained
// before their wave crossed BAR(t-1).
// LDS swizzle (proven, conflicts=0): row of 32 elems = 4 chunks of 16B;
// logical chunk c at physical (c + (row>>1))&3; global source pre-rotated.
// MODE: 0 = rect grid (XCD col-major swizzle if SWZ: same-XCD share B panel);
//       1 = att@v: flat 512-block grid, split-K z=2 into CONTIGUOUS disjoint
//           fp32 partials (Cv + z*SEQ*FEAT floats, plain stores, no atomics).
//           r9 FIX: launcher now allocates the two partials contiguously --
//           r8 passed separated regions while the kernel offsets from base
//           (z=1 wrote past sc0; add2 read stale qkvb -> absmax 5.35).
//           Complementary halves: f<256 bi descending, f>=256 bi ascending
//           -> round-robin CU pairing gives 66 phases/CU constant.

#define BARW() asm volatile("s_barrier" ::: "memory")
#define VMC6() asm volatile("s_waitcnt vmcnt(6)" ::: "memory")
#define LGKM0() asm volatile("s_waitcnt lgkmcnt(0)" ::: "memory")

#define STAGE(SB, KO) do { \
  u16* Lb = &LDSU[SB][0] + w * 512; \
  gld_lds16(pA0 + (KO), Lb); \
  gld_lds16(pA0 + (size_t)64 * LDA_ + (KO), Lb + 2048); \
  gld_lds16(pB0 + (KO), Lb + 4096); \
  gld_lds16(pB0 + (size_t)64 * LDB_ + (KO), Lb + 4096 + 2048); \
  gld_lds16(pB0 + (size_t)128 * LDB_ + (KO), Lb + 4096 + 4096); \
  gld_lds16(pB0 + (size_t)192 * LDB_ + (KO), Lb + 4096 + 6144); \
} while (0)

#define LOADA(BUF) do { _Pragma("unroll") \
  for (int mi = 0; mi < 8; ++mi) \
    af[mi] = *(const v8s*)(&LDSU[BUF][0] + (mi * 16 + lm) * 32 + lqs); \
} while (0)

#define LOADB(BUF) do { _Pragma("unroll") \
  for (int ni = 0; ni < 4; ++ni) \
    bf4[ni] = *(const v8s*)(&LDSU[BUF][0] + 4096 + (w * 64 + ni * 16 + lm) * 32 + lqs); \
} while (0)

template<int LDA_, int LDB_, int LDC_, int OUTMODE /*0=bf16 store, 1=fp32 store*/,
         int ADDB, int MODE, int SWZ>
__global__ __launch_bounds__(256, 2) void gemmw(
    const u16* __restrict__ A, const u16* __restrict__ B,
    void* __restrict__ Cv, int K,
    const float* __restrict__ bias, float scale) {
  int bi, bj, ks, ke;
  if (MODE == 1) {
    // att@v flat grid, 512 blocks: complementary desc/asc halves
    const int f = blockIdx.x;
    const int r = f & 255;
    const int h = f >> 8;            // 0: bi descending, 1: bi ascending
    const int g = r >> 4;            // 0..15
    bi = h ? g : 31 - g;
    const int idx = r & 15;
    bj = idx >> 1;
    const int z = idx & 1;
    const int kq = (bi + 1) * 64;
    ks = z ? kq : 0;  ke = ks + kq;  // nt = 2*(bi+1), even, >= 2
    Cv = (void*)((float*)Cv + (size_t)z * SEQ * FEAT);  // contiguous partial z
  } else {
    if (SWZ) {
      // column-major within XCD chunk: same-XCD neighbors share the B panel
      const int gx = gridDim.x, gy = gridDim.y;
      const int b = blockIdx.y * gx + blockIdx.x;
      const int cpx = (gx * gy) >> 3;            // nwg % 8 == 0
      const int s = (b & 7) * cpx + (b >> 3);
      bi = s % gy;  bj = s / gy;
    } else { bj = blockIdx.x; bi = blockIdx.y; }
    ks = 0; ke = K;
  }
  const int i0 = bi * 128, j0 = bj * 256;

  // [buf][ A: 128 rows x 32 (4096 elems) | B: 256 rows x 32 (8192 elems) ]
  __shared__ u16 LDSU[3][12288];   // 72 KiB

  const int t = threadIdx.x;
  const int w = t >> 6, l = t & 63;
  const int lm = l & 15, lq = l >> 4;
  // fragment read: physical chunk = (lq + (row>>1)) & 3; row bases are
  // multiples of 8 => (row>>1)&3 == (lm>>1)&3
  const int lqs = ((lq + (lm >> 1)) & 3) * 8;

  // staging: wave w handles instrs covering 16-row groups; lane l: row =
  // base + (l>>2), physical chunk l&3, logical = ((l&3)-((row>>1)&3))&3.
  const int rA = w * 16 + (l >> 2);
  const int cA = ((((l & 3) - ((rA >> 1) & 3)) & 3)) * 8;
  const u16* pA0 = A + (size_t)(i0 + rA) * LDA_ + cA;
  const u16* pB0 = B + (size_t)(j0 + rA) * LDB_ + cA;

  v4f acc[8][4];
#pragma unroll
  for (int a = 0; a < 8; ++a)
#pragma unroll
    for (int b2 = 0; b2 < 4; ++b2)
      acc[a][b2] = v4f{0.f, 0.f, 0.f, 0.f};

  v8s af[8], bf4[4];

  // prologue: stage tiles 0 (buf0) and 1 (buf1); vmcnt(6) -> tile0 landed
  STAGE(0, ks); STAGE(1, ks + 32);
  VMC6(); BARW();
  LOADB(0);                           // B fragments of tile 0 -> regs

  const int nt = (ke - ks) >> 5;      // even, >= 2 in all modes
  int b0 = 0, b1 = 1;
  for (int tt = 0; tt < nt; tt += 2) {
    const int kc = ks + (tt << 5);
    const int s2 = 3 - b0 - b1;       // the third buffer
    // sub-phase 0: compute tile tt (A in b0, B preloaded in bf4)
    {
      const int kst = (kc + 64 < ke) ? kc + 64 : ks;   // A+B tile tt+2
      STAGE(s2, kst);
      LOADA(b0);
      __builtin_amdgcn_s_setprio(1);
#pragma unroll
      for (int mi = 0; mi < 8; ++mi)
#pragma unroll
        for (int ni = 0; ni < 4; ++ni)
          acc[mi][ni] = __builtin_amdgcn_mfma_f32_16x16x32_bf16(af[mi], bf4[ni], acc[mi][ni], 0, 0, 0);
      __builtin_amdgcn_s_setprio(0);
      VMC6(); BARW();                 // tile tt+1 landed (all waves)
      LOADB(b1);                      // B fragments of tile tt+1 -> regs
    }
    // sub-phase 1: compute tile tt+1 (A in b1)
    {
      const int kst = (kc + 96 < ke) ? kc + 96 : ks;   // tile tt+3 (clamped)
      STAGE(b0, kst);
      LOADA(b1);
      __builtin_amdgcn_s_setprio(1);
#pragma unroll
      for (int mi = 0; mi < 8; ++mi)
#pragma unroll
        for (int ni = 0; ni < 4; ++ni)
          acc[mi][ni] = __builtin_amdgcn_mfma_f32_16x16x32_bf16(af[mi], bf4[ni], acc[mi][ni], 0, 0, 0);
      __builtin_amdgcn_s_setprio(0);
      VMC6(); BARW();                 // tile tt+2 landed
      LOADB(s2);                      // B fragments of tile tt+2 -> regs
    }
    b1 = b0; b0 = s2;                 // bufs advance by 2 tiles
  }

  // epilogue: C/D layout col=lane&15, row=quad*4+reg [m89-verified]
#pragma unroll
  for (int mi = 0; mi < 8; ++mi) {
#pragma unroll
    for (int ni = 0; ni < 4; ++ni) {
      const int cc = j0 + w * 64 + ni * 16 + lm;
      const float badd = ADDB ? bias[cc] : 0.f;
#pragma unroll
      for (int r = 0; r < 4; ++r) {
        const int rr = i0 + mi * 16 + lq * 4 + r;
        if (OUTMODE == 0)
          ((u16*)Cv)[(size_t)rr * LDC_ + cc] = f2bf(acc[mi][ni][r] * scale + badd);
        else
          ((float*)Cv)[(size_t)rr * LDC_ + cc] = acc[mi][ni][r];
      }
    }
  }
}

#undef STAGE
#undef LOADA
#undef LOADB

// ---------- gemm8tri: 256x256 8-phase GEMM on a flat triangular grid ----------
// r1/r7-verified schedule deployed where its 1-block/CU occupancy is free:
// GEMM2's 136-block grid (0.53 rounds -> makespan = ONE block-time).
// C[M,N] = A[M,K]*B[N,K]^T, bf16, 512 thr = 8 waves (2Mx4N), wave owns 128x64,
// BK=64, double-buffered LDS 128 KiB, K % 128 == 0.
// Per K-tile: 4 quadrant phases; 1 half-tile (2 x gld_lds16) staged per phase;
// counted vmcnt(6) ONLY at phases 4/8; raw s_barrier (no drain).
// LDS swizzle: row of 64 elems = 8 chunks of 16B, logical chunk c at physical
// (c + row) & 7; global source pre-rotated (both-sides rule).

#define LDA8(BUF, MH) do { _Pragma("unroll") \
  for (int fi = 0; fi < 4; ++fi) { \
    const u16* ap = &As8[BUF][wr][(MH) * 4096 + fi * 1024]; \
    af[fi][0] = *(const v8s*)(ap + off0); \
    af[fi][1] = *(const v8s*)(ap + off1); \
  } } while (0)

#define LDB8(BUF) do { _Pragma("unroll") \
  for (int ni = 0; ni < 4; ++ni) { \
    const u16* bp = &Bs8[BUF][bh][bo + ni * 1024]; \
    bfr[ni][0] = *(const v8s*)(bp + off0); \
    bfr[ni][1] = *(const v8s*)(bp + off1); \
  } } while (0)

#define MMA8(MH, NL) do { _Pragma("unroll") \
  for (int fi = 0; fi < 4; ++fi) { _Pragma("unroll") \
    for (int nn = 0; nn < 2; ++nn) { \
      acc[(MH)*4+fi][(NL)+nn] = __builtin_amdgcn_mfma_f32_16x16x32_bf16( \
          af[fi][0], bfr[(NL)+nn][0], acc[(MH)*4+fi][(NL)+nn], 0, 0, 0); \
      acc[(MH)*4+fi][(NL)+nn] = __builtin_amdgcn_mfma_f32_16x16x32_bf16( \
          af[fi][1], bfr[(NL)+nn][1], acc[(MH)*4+fi][(NL)+nn], 0, 0, 0); \
    } } } while (0)

#define STG8A(BUF, H, KO) do { \
  gld_lds16(Ag + (size_t)(H) * 128 * LDA_ + (KO), &As8[BUF][H][w8 * 1024]); \
  gld_lds16(Ag + ((size_t)(H) * 128 + 8) * LDA_ + (KO), &As8[BUF][H][w8 * 1024 + 512]); \
  } while (0)

#define STG8B(BUF, H, KO) do { \
  gld_lds16(Bg + (size_t)(H) * 128 * LDB_ + (KO), &Bs8[BUF][H][w8 * 1024]); \
  gld_lds16(Bg + ((size_t)(H) * 128 + 8) * LDB_ + (KO), &Bs8[BUF][H][w8 * 1024 + 512]); \
  } while (0)

template<int LDA_, int LDB_, int LDC_>
__global__ __launch_bounds__(512, 2) void gemm8tri(
    const u16* __restrict__ A, const u16* __restrict__ B,
    u16* __restrict__ C, int K, float scale) {
  // flat lower-triangular grid (bj <= bi), XCD-chunked; gridDim.x % 8 == 0
  const int b = blockIdx.x;
  const int cpx = (int)gridDim.x >> 3;
  const int s = (b & 7) * cpx + (b >> 3);
  int bi = (int)((sqrtf(8.f * s + 1.f) - 1.f) * 0.5f);
  while ((bi + 1) * (bi + 2) / 2 <= s) ++bi;
  while (bi * (bi + 1) / 2 > s) --bi;
  const int bj = s - bi * (bi + 1) / 2;
  const int i0 = bi * 256, j0 = bj * 256;

  __shared__ u16 As8[2][2][8192];  // [buf][half][128*64], 64 KiB
  __shared__ u16 Bs8[2][2][8192];  // 64 KiB

  const int t = threadIdx.x;
  const int w8 = t >> 6, l = t & 63;
  const int wr = w8 >> 2, wc = w8 & 3;
  const int lm = l & 15, lq = l >> 4;
  const int bh = wc >> 1, bo = (wc & 1) * 4096;

  // fragment-read offsets within a half (chunk rotation, conflicts=0 r1)
  const int off0 = lm * 64 + ((lq + lm) & 7) * 8;        // s=0
  const int off1 = lm * 64 + ((lq + lm + 4) & 7) * 8;    // s=1

  // staging: row = w8*16 + (l>>3); logical col chunk = ((l&7) - (l>>3)) & 7
  const int srow = w8 * 16 + (l >> 3);
  const int scol = (((l & 7) - (l >> 3)) & 7) * 8;
  const u16* Ag = A + (size_t)(i0 + srow) * LDA_ + scol;
  const u16* Bg = B + (size_t)(j0 + srow) * LDB_ + scol;

  v4f acc[8][4];
#pragma unroll
  for (int a = 0; a < 8; ++a)
#pragma unroll
    for (int b2 = 0; b2 < 4; ++b2)
      acc[a][b2] = v4f{0.f, 0.f, 0.f, 0.f};

  v8s af[4][2], bfr[4][2];

  // prologue: tile0 -> buf0 (B0,B1,A0,A1), tile1 -> buf1 (B0,B1,A0).
  // 14 loads; vmcnt(6) -> oldest 8 (all of buf0) landed.
  STG8B(0, 0, 0); STG8B(0, 1, 0); STG8A(0, 0, 0); STG8A(0, 1, 0);
  STG8B(1, 0, 64); STG8B(1, 1, 64); STG8A(1, 0, 64);
  VMC6(); BARW();

  const int nit = K >> 7;  // K % 128 == 0
  for (int it = 0; it < nit; ++it) {
    const int kc = it << 7;
    const int k1 = kc + 64;                     // tile 2it+1 (always valid)
    int k2 = kc + 128; if (k2 >= K) k2 = 0;     // clamped stages never read
    int k3 = kc + 192; if (k3 >= K) k3 = 0;

    // P1: Q(m0, n0..1) on buf0
    LDA8(0, 0); LDB8(0);
    STG8A(1, 1, k1);
    BARW(); LGKM0();
    __builtin_amdgcn_s_setprio(1); MMA8(0, 0); __builtin_amdgcn_s_setprio(0);
    BARW();
    // P2: Q(m0, n2..3)
    STG8B(0, 0, k2);
    BARW();
    __builtin_amdgcn_s_setprio(1); MMA8(0, 2); __builtin_amdgcn_s_setprio(0);
    BARW();
    // P3: Q(m1, n0..1)
    LDA8(0, 1);
    STG8B(0, 1, k2);
    BARW(); LGKM0();
    __builtin_amdgcn_s_setprio(1); MMA8(1, 0); __builtin_amdgcn_s_setprio(0);
    BARW();
    // P4: Q(m1, n2..3); counted wait -> buf1 fully landed before P5
    STG8A(0, 0, k2);
    BARW();
    __builtin_amdgcn_s_setprio(1); MMA8(1, 2); __builtin_amdgcn_s_setprio(0);
    VMC6(); BARW();
    // P5: Q(m0, n0..1) on buf1
    LDA8(1, 0); LDB8(1);
    STG8A(0, 1, k2);
    BARW(); LGKM0();
    __builtin_amdgcn_s_setprio(1); MMA8(0, 0); __builtin_amdgcn_s_setprio(0);
    BARW();
    // P6: Q(m0, n2..3)
    STG8B(1, 0, k3);
    BARW();
    __builtin_amdgcn_s_setprio(1); MMA8(0, 2); __builtin_amdgcn_s_setprio(0);
    BARW();
    // P7: Q(m1, n0..1)
    LDA8(1, 1);
    STG8B(1, 1, k3);
    BARW(); LGKM0();
    __builtin_amdgcn_s_setprio(1); MMA8(1, 0); __builtin_amdgcn_s_setprio(0);
    BARW();
    // P8: Q(m1, n2..3); counted wait -> buf0 fully landed before next P1
    STG8A(1, 0, k3);
    BARW();
    __builtin_amdgcn_s_setprio(1); MMA8(1, 2); __builtin_amdgcn_s_setprio(0);
    VMC6(); BARW();
  }

  // epilogue: C/D layout col=lane&15, row=quad*4+reg [m89-verified]
#pragma unroll
  for (int mi = 0; mi < 8; ++mi) {
#pragma unroll
    for (int ni = 0; ni < 4; ++ni) {
      const int cc = j0 + wc * 64 + ni * 16 + lm;
#pragma unroll
      for (int r = 0; r < 4; ++r) {
        const int rr = i0 + wr * 128 + mi * 16 + lq * 4 + r;
        C[(size_t)rr * LDC_ + cc] = f2bf(acc[mi][ni][r] * scale);
      }
    }
  }
}

#undef LDA8
#undef LDB8
#undef MMA8
#undef STG8A
#undef STG8B

// ---------- row softmax with causal + padding mask (single bf16 input) ----------
__global__ __launch_bounds__(256) void softmax_rows(
    const u16* __restrict__ S0,
    u16* __restrict__ att, const int* __restrict__ npad_p) {
  const int i = blockIdx.x;
  const int np = *npad_p;
  const int kend = ((i >> 7) + 1) << 7;   // 128-rounded: matches attV read range
  const u16* r0 = S0 + (size_t)i * SEQ;
  u16* arow = att + (size_t)i * SEQ;
  const int t = threadIdx.x;

  float m = -3.0e38f, s = 0.f;
  for (int j = np + t; j <= i; j += 256) {
    float v = bf2f(r0[j]);
    if (v > m) { s = s * __expf(m - v) + 1.f; m = v; }
    else       { s += __expf(v - m); }
  }
#pragma unroll
  for (int off = 32; off > 0; off >>= 1) {
    float mo = __shfl_xor(m, off);
    float so = __shfl_xor(s, off);
    float M = fmaxf(m, mo);
    s = s * __expf(m - M) + so * __expf(mo - M);
    m = M;
  }
  __shared__ float sm[4], ss[4];
  const int w = t >> 6, l = t & 63;
  if (l == 0) { sm[w] = m; ss[w] = s; }
  __syncthreads();
  const float M = fmaxf(fmaxf(sm[0], sm[1]), fmaxf(sm[2], sm[3]));
  const float Ssum = ss[0] * __expf(sm[0] - M) + ss[1] * __expf(sm[1] - M) +
                     ss[2] * __expf(sm[2] - M) + ss[3] * __expf(sm[3] - M);
  const float inv = 1.f / Ssum;  // padded rows masked to 0 below; inv unused there

  for (int j0b = t * 8; j0b < kend; j0b += 2048) {
    union { u16 s8[8]; uint4 v; } u;
#pragma unroll
    for (int q = 0; q < 8; ++q) {
      const int j = j0b + q;
      float a = 0.f;
      if (j >= np && j <= i)
        a = __expf(bf2f(r0[j]) - M) * inv;
      u.s8[q] = f2bf(a);
    }
    *(uint4*)(arow + j0b) = u.v;
  }
}

// ---------- launch ----------

extern "C" void kernel_launch(void* const* d_in, const int* in_sizes, int n_in,
                              void* d_out, int out_size, void* d_ws, size_t ws_size,
                              hipStream_t stream) {
  const float* x = (const float*)d_in[0];
  const float* W = (const float*)d_in[1];
  const float* b = (const float*)d_in[2];
  const int* npad = (const int*)d_in[3];
  float* out = (float*)d_out;

  // workspace (168 MB, same footprint as the r0 baseline):
  // [xb 16MB | Wt 24MB] reused as att 32MB ][ qkvb 48MB ][ vt 16MB ]
  // [ sc0 32MB -> p0 ][ sc1 32MB -> p1 ]   (p0/p1 CONTIGUOUS: kernel offsets
  //                                         partial z by z*SEQ*FEAT floats)
  char* p = (char*)d_ws;
  u16* xb = (u16*)p;
  u16* Wt = (u16*)(p + (size_t)SEQ * FEAT * 2);
  u16* att = (u16*)p;
  p += (size_t)SEQ * FEAT * 2 + (size_t)F3 * FEAT * 2;
  u16* qkvb = (u16*)p;  p += (size_t)SEQ * F3 * 2;
  u16* vt   = (u16*)p;  p += (size_t)FEAT * SEQ * 2;
  u16* sc0  = (u16*)p;  p += (size_t)SEQ * SEQ * 2;   // bf16 scores -> fp32 p0
  p += (size_t)SEQ * SEQ * 2;                         // fp32 p1 (contiguous)
  if (ws_size < (size_t)(p - (char*)d_ws)) return;

  float* p0 = (float*)sc0;                    // partial z=0 (32MB)
  float* p1 = p0 + (size_t)SEQ * FEAT;        // partial z=1 (next 32MB)

  const float scale = 0.02209708691207961f;  // 1/sqrt(2048)

  cvt_f32_bf16<<<SEQ * FEAT / 8 / 256, 256, 0, stream>>>(x, xb, SEQ * FEAT / 8);
  transp_f2b<<<dim3(F3 / 32, FEAT / 32), dim3(32, 8), 0, stream>>>(W, F3, Wt, FEAT);
  // qkv = x @ W + b: 128x256 tiles, grid 24x32 = 768 blocks (2 blocks/CU)
  gemmw<FEAT, FEAT, F3, 0, 1, 0, 1><<<dim3(F3 / 256, SEQ / 128), 256, 0, stream>>>(
      xb, Wt, (void*)qkvb, FEAT, b, 1.0f);
  transp_b2b<<<dim3(FEAT / 32, SEQ / 32), dim3(32, 8), 0, stream>>>(
      qkvb + 2 * FEAT, F3, vt, SEQ);
  // scores = (q @ k^T)/sqrt(F): 8-phase 256^2, flat triangular grid 16*17/2 =
  // 136 blocks (1 block/CU, 0.53 rounds -> makespan = one block-time)
  gemm8tri<F3, F3, SEQ><<<dim3(136), 512, 0, stream>>>(
      qkvb, qkvb + FEAT, sc0, FEAT, scale);
  softmax_rows<<<SEQ, 256, 0, stream>>>(sc0, att, npad);
  // out = att @ v: split-K z=2 -> contiguous disjoint fp32 partials p0/p1
  // (plain stores, no atomics); complementary desc/asc halves -> 66 phases/CU
  gemmw<SEQ, SEQ, FEAT, 1, 0, 1, 0><<<dim3(512), 256, 0, stream>>>(
      att, vt, (void*)p0, 0, nullptr, 1.0f);
  // out = p0 + p1
  add2_f32<<<SEQ * FEAT / 4 / 256, 256, 0, stream>>>(p0, p1, out, SEQ * FEAT / 4);
}